// Round 1
// baseline (407.847 us; speedup 1.0000x reference)
//
#include <hip/hip_runtime.h>
#include <stdint.h>

#define NPTS 8192
#define DIM  512
#define ODIM 512

typedef __attribute__((ext_vector_type(8))) short short8;
typedef __attribute__((ext_vector_type(4))) float f32x4;

__device__ __forceinline__ void gload_lds16(const void* g, void* l) {
  __builtin_amdgcn_global_load_lds(
      (__attribute__((address_space(1))) void*)g,
      (__attribute__((address_space(3))) void*)l, 16, 0, 0);
}

// round-to-nearest-even f32 -> bf16 bits (values are finite here)
__device__ __forceinline__ short f2bf(float f) {
  uint32_t u = __float_as_uint(f);
  u = (u + 0x7FFFu + ((u >> 16) & 1u)) >> 16;
  return (short)u;
}

// C[128x128] += A[128xK] * B'[128xK]^T ; A,B' row-major, K contiguous (NT GEMM).
// 256 threads = 4 waves (2x2). BK=32. m97-style: global_load_lds(16B) staging,
// ds_read_b128 frags, 16x mfma_f32_16x16x32_bf16 per K-step.
__device__ __forceinline__ void gemm_core_nt(const short* __restrict__ A,
                                             const short* __restrict__ B,
                                             int K, int lda, int ldb,
                                             short* smem, f32x4 acc[4][4]) {
  const int tid  = threadIdx.x;
  const int wid  = tid >> 6;
  const int lane = tid & 63;
  const int wr = wid >> 1, wc = wid & 1;
  const int sr = lane >> 2;         // staging row within 16-row group
  const int sc = (lane & 3) << 3;   // staging col chunk (8 bf16 = 16B)
  const int fr = lane & 15, fg = lane >> 4;
  short* sA = smem;
  short* sB = smem + 4096;
  // wave-uniform LDS destinations (HW adds lane*16B)
  short* dA0 = sA + wid * 512;
  short* dA1 = sA + 2048 + wid * 512;
  short* dB0 = sB + wid * 512;
  short* dB1 = sB + 2048 + wid * 512;
  const short* pa0 = A + (size_t)(wid * 16 + sr) * lda + sc;
  const short* pa1 = A + (size_t)(64 + wid * 16 + sr) * lda + sc;
  const short* pb0 = B + (size_t)(wid * 16 + sr) * ldb + sc;
  const short* pb1 = B + (size_t)(64 + wid * 16 + sr) * ldb + sc;

  for (int k0 = 0; k0 < K; k0 += 32) {
    gload_lds16(pa0 + k0, dA0);
    gload_lds16(pa1 + k0, dA1);
    gload_lds16(pb0 + k0, dB0);
    gload_lds16(pb1 + k0, dB1);
    __syncthreads();   // drains vmcnt -> staged tile visible
    short8 af[4], bb[4];
#pragma unroll
    for (int m = 0; m < 4; ++m)
      af[m] = *(const short8*)(sA + (wr * 64 + m * 16 + fr) * 32 + fg * 8);
#pragma unroll
    for (int n = 0; n < 4; ++n)
      bb[n] = *(const short8*)(sB + (wc * 64 + n * 16 + fr) * 32 + fg * 8);
#pragma unroll
    for (int m = 0; m < 4; ++m)
#pragma unroll
      for (int n = 0; n < 4; ++n)
        acc[m][n] = __builtin_amdgcn_mfma_f32_16x16x32_bf16(af[m], bb[n], acc[m][n], 0, 0, 0);
    __syncthreads();   // all reads done before next overwrite
  }
}

#define ZERO_ACC(acc)                        \
  {                                          \
    f32x4 _z = {0.f, 0.f, 0.f, 0.f};         \
    _Pragma("unroll")                        \
    for (int m = 0; m < 4; ++m)              \
      _Pragma("unroll")                      \
      for (int n = 0; n < 4; ++n) acc[m][n] = _z; \
  }

// K1: x (f32) -> xb (bf16), sq[i] = sum x[i]^2. One wave per row.
__global__ __launch_bounds__(256) void k_prep_x(const float* __restrict__ x,
                                                short* __restrict__ xb,
                                                float* __restrict__ sq) {
  const int row  = blockIdx.x * 4 + (threadIdx.x >> 6);
  const int lane = threadIdx.x & 63;
  const float* px = x + (size_t)row * DIM + lane * 8;
  const float4 v0 = *(const float4*)px;
  const float4 v1 = *(const float4*)(px + 4);
  float s = v0.x*v0.x + v0.y*v0.y + v0.z*v0.z + v0.w*v0.w +
            v1.x*v1.x + v1.y*v1.y + v1.z*v1.z + v1.w*v1.w;
  short8 o;
  o[0]=f2bf(v0.x); o[1]=f2bf(v0.y); o[2]=f2bf(v0.z); o[3]=f2bf(v0.w);
  o[4]=f2bf(v1.x); o[5]=f2bf(v1.y); o[6]=f2bf(v1.z); o[7]=f2bf(v1.w);
  *(short8*)(xb + (size_t)row * DIM + lane * 8) = o;
#pragma unroll
  for (int m = 32; m >= 1; m >>= 1) s += __shfl_xor(s, m);
  if (lane == 0) sq[row] = s;
}

// K1b: W (f32) -> Wb (bf16)
__global__ __launch_bounds__(256) void k_prep_w(const float* __restrict__ W,
                                                short* __restrict__ Wb) {
  const int idx = blockIdx.x * 256 + threadIdx.x;  // 8 elems each
  const float4 v0 = *(const float4*)(W + (size_t)idx * 8);
  const float4 v1 = *(const float4*)(W + (size_t)idx * 8 + 4);
  short8 o;
  o[0]=f2bf(v0.x); o[1]=f2bf(v0.y); o[2]=f2bf(v0.z); o[3]=f2bf(v0.w);
  o[4]=f2bf(v1.x); o[5]=f2bf(v1.y); o[6]=f2bf(v1.z); o[7]=f2bf(v1.w);
  *(short8*)(Wb + (size_t)idx * 8) = o;
}

// K2: YbT[o][i] = bf16( sum_d Wb[o][d] * xb[i][d] )   (Y = x@W.T, stored transposed)
__global__ __launch_bounds__(256) void k_ybt(const short* __restrict__ xb,
                                             const short* __restrict__ Wb,
                                             short* __restrict__ YbT) {
  __shared__ short smem[8192];
  f32x4 acc[4][4];
  ZERO_ACC(acc);
  const int rowBase = blockIdx.y * 128;  // o
  const int colBase = blockIdx.x * 128;  // i
  gemm_core_nt(Wb + (size_t)rowBase * DIM, xb + (size_t)colBase * DIM,
               DIM, DIM, DIM, smem, acc);
  const int lane = threadIdx.x & 63, wid = threadIdx.x >> 6;
  const int wr = wid >> 1, wc = wid & 1, fr = lane & 15, fg = lane >> 4;
#pragma unroll
  for (int m = 0; m < 4; ++m)
#pragma unroll
    for (int n = 0; n < 4; ++n)
#pragma unroll
      for (int r = 0; r < 4; ++r) {
        const int ro = rowBase + wr * 64 + m * 16 + fg * 4 + r;
        const int ci = colBase + wc * 64 + n * 16 + fr;
        YbT[(size_t)ro * NPTS + ci] = f2bf(acc[m][n][r]);
      }
}

// K3: P[i][j] = bf16( exp( min(2*dot - sq_i - sq_j, 0) / (2*sigma^2) ) ), rowsum += per-row sums
__global__ __launch_bounds__(256) void k_pmat(const short* __restrict__ xb,
                                              const float* __restrict__ sq,
                                              short* __restrict__ P,
                                              float* __restrict__ rowsum,
                                              int jbase, int SW) {
  __shared__ short smem[8192];
  f32x4 acc[4][4];
  ZERO_ACC(acc);
  const int rowBase = blockIdx.y * 128;      // i
  const int colTile = blockIdx.x * 128;      // j within strip
  const int jglob = jbase + colTile;
  gemm_core_nt(xb + (size_t)rowBase * DIM, xb + (size_t)jglob * DIM,
               DIM, DIM, DIM, smem, acc);
  const int lane = threadIdx.x & 63, wid = threadIdx.x >> 6;
  const int wr = wid >> 1, wc = wid & 1, fr = lane & 15, fg = lane >> 4;
  float sj[4];
#pragma unroll
  for (int n = 0; n < 4; ++n) sj[n] = sq[jglob + wc * 64 + n * 16 + fr];
#pragma unroll
  for (int m = 0; m < 4; ++m) {
#pragma unroll
    for (int r = 0; r < 4; ++r) {
      const int i = rowBase + wr * 64 + m * 16 + fg * 4 + r;
      const float si = sq[i];
      float rs = 0.f;
#pragma unroll
      for (int n = 0; n < 4; ++n) {
        const float t = fminf(2.f * acc[m][n][r] - si - sj[n], 0.f) * (1.0f / 2048.0f);
        const float w = __expf(t);
        rs += w;
        P[(size_t)i * SW + (colTile + wc * 64 + n * 16 + fr)] = f2bf(w);
      }
      // reduce over the 16 fr-lanes (same fg group), then 1 atomic per row
      rs += __shfl_xor(rs, 1);
      rs += __shfl_xor(rs, 2);
      rs += __shfl_xor(rs, 4);
      rs += __shfl_xor(rs, 8);
      if (fr == 0) atomicAdd(&rowsum[i], rs);
    }
  }
}

// K4: out_acc[i][o] += sum_j P[i][j] * YbT[o][j]   (NT GEMM, K split by blockIdx.z)
__global__ __launch_bounds__(256) void k_pv(const short* __restrict__ P,
                                            const short* __restrict__ YbT,
                                            float* __restrict__ out_acc,
                                            int jbase, int SW, int klen) {
  __shared__ short smem[8192];
  f32x4 acc[4][4];
  ZERO_ACC(acc);
  const int rowBase = blockIdx.y * 128;  // i
  const int colBase = blockIdx.x * 128;  // o
  const int kz = blockIdx.z * klen;
  gemm_core_nt(P + (size_t)rowBase * SW + kz,
               YbT + (size_t)colBase * NPTS + jbase + kz,
               klen, SW, NPTS, smem, acc);
  const int lane = threadIdx.x & 63, wid = threadIdx.x >> 6;
  const int wr = wid >> 1, wc = wid & 1, fr = lane & 15, fg = lane >> 4;
#pragma unroll
  for (int m = 0; m < 4; ++m)
#pragma unroll
    for (int n = 0; n < 4; ++n)
#pragma unroll
      for (int r = 0; r < 4; ++r) {
        const int i = rowBase + wr * 64 + m * 16 + fg * 4 + r;
        const int o = colBase + wc * 64 + n * 16 + fr;
        atomicAdd(&out_acc[(size_t)i * ODIM + o], acc[m][n][r]);
      }
}

// K5: out = out_acc / (rowsum + eps) + b
__global__ __launch_bounds__(256) void k_final(const float* __restrict__ out_acc,
                                               const float* __restrict__ rowsum,
                                               const float* __restrict__ bvec,
                                               float* __restrict__ out) {
  const int idx = blockIdx.x * 256 + threadIdx.x;  // one float4 each
  const int i = idx >> 7;
  const int o = (idx & 127) << 2;
  const float inv = 1.f / (rowsum[i] + 1e-8f);
  const float4 a = *(const float4*)(out_acc + (size_t)i * ODIM + o);
  const float4 bb = *(const float4*)(bvec + o);
  float4 r;
  r.x = a.x * inv + bb.x;
  r.y = a.y * inv + bb.y;
  r.z = a.z * inv + bb.z;
  r.w = a.w * inv + bb.w;
  *(float4*)(out + (size_t)i * ODIM + o) = r;
}

extern "C" void kernel_launch(void* const* d_in, const int* in_sizes, int n_in,
                              void* d_out, int out_size, void* d_ws, size_t ws_size,
                              hipStream_t stream) {
  (void)in_sizes; (void)n_in; (void)out_size;
  const float* x = (const float*)d_in[0];
  const float* W = (const float*)d_in[1];
  const float* bvec = (const float*)d_in[2];
  float* out = (float*)d_out;
  char* ws = (char*)d_ws;

  // workspace carving (bytes)
  short* xb      = (short*)(ws + 0);                  //  8 MiB
  short* Wb      = (short*)(ws + 8388608);            //  0.5 MiB
  short* YbT     = (short*)(ws + 8912896);            //  8 MiB
  float* sq      = (float*)(ws + 17301504);           //  32 KiB
  float* rowsum  = (float*)(ws + 17334272);           //  32 KiB
  float* out_acc = (float*)(ws + 17367040);           //  16 MiB
  short* P       = (short*)(ws + 34144256);           //  up to 128 MiB

  // adaptive P-strip width so everything fits in ws
  size_t pav = ws_size > 34144256 ? ws_size - 34144256 : 0;
  int SW = 8192;
  while (SW > 128 && (size_t)NPTS * SW * 2 > pav) SW >>= 1;
  const int nstrips = NPTS / SW;
  int ksplit = SW / 2048;
  if (ksplit < 1) ksplit = 1;
  if (ksplit > 4) ksplit = 4;
  const int klen = SW / ksplit;

  hipMemsetAsync(rowsum, 0, NPTS * sizeof(float), stream);
  hipMemsetAsync(out_acc, 0, (size_t)NPTS * ODIM * sizeof(float), stream);

  k_prep_x<<<dim3(NPTS / 4), 256, 0, stream>>>(x, xb, sq);
  k_prep_w<<<dim3(ODIM * DIM / 8 / 256), 256, 0, stream>>>(W, Wb);
  k_ybt<<<dim3(NPTS / 128, ODIM / 128), 256, 0, stream>>>(xb, Wb, YbT);

  for (int s = 0; s < nstrips; ++s) {
    const int jbase = s * SW;
    k_pmat<<<dim3(SW / 128, NPTS / 128), 256, 0, stream>>>(xb, sq, P, rowsum, jbase, SW);
    k_pv<<<dim3(ODIM / 128, NPTS / 128, ksplit), 256, 0, stream>>>(P, YbT, out_acc, jbase, SW, klen);
  }

  k_final<<<dim3(NPTS * ODIM / 4 / 256), 256, 0, stream>>>(out_acc, rowsum, bvec, out);
}

// Round 2
// 360.488 us; speedup vs baseline: 1.1314x; 1.1314x over previous
//
#include <hip/hip_runtime.h>
#include <stdint.h>

#define NPTS 8192
#define DIM  512
#define ODIM 512

typedef __attribute__((ext_vector_type(8))) short short8;
typedef __attribute__((ext_vector_type(4))) float f32x4;

__device__ __forceinline__ void gload_lds16(const void* g, void* l) {
  __builtin_amdgcn_global_load_lds(
      (__attribute__((address_space(1))) void*)g,
      (__attribute__((address_space(3))) void*)l, 16, 0, 0);
}

// round-to-nearest-even f32 -> bf16 bits (values are finite here)
__device__ __forceinline__ short f2bf(float f) {
  uint32_t u = __float_as_uint(f);
  u = (u + 0x7FFFu + ((u >> 16) & 1u)) >> 16;
  return (short)u;
}

// ---------------------------------------------------------------------------
// 256x256 tile, BK=64, 8 waves (2x4), double-buffered 2-phase prefetch.
// C[256x256] += A[256xK] * B'[256xK]^T ; A,B' row-major along K (NT GEMM).
// LDS: 2 buffers x (A 256x64 + B 256x64) bf16 = 128 KiB.
// Per K-tile per wave: 24 ds_read_b128 + 64 mfma_f32_16x16x32_bf16.
// One vmcnt-draining __syncthreads per K-tile; next tile's global_load_lds
// issued BEFORE current tile's compute (T3 minimum-2-phase recipe).
// ---------------------------------------------------------------------------
__device__ __forceinline__ void gemm256_2ph(const short* __restrict__ A,
                                            const short* __restrict__ B,
                                            int K, int lda, int ldb,
                                            short* lds, f32x4 acc[8][4]) {
  const int tid  = threadIdx.x;
  const int wid  = tid >> 6;
  const int lane = tid & 63;
  const int wr = wid >> 2, wc = wid & 3;          // wave grid 2x4
  const int fr = lane & 15, fg = lane >> 4;       // mfma fragment coords
  const int srow = lane >> 3;                     // staging row in 8-row group
  const int scol = (lane & 7) << 3;               // staging col (8 bf16 = 16B)

  const short* sa[4];
  const short* sb[4];
  int da[4];
#pragma unroll
  for (int q = 0; q < 4; ++q) {
    const int gi = q * 8 + wid;                   // 0..31, 8 rows each
    sa[q] = A + (size_t)(gi * 8 + srow) * lda + scol;
    sb[q] = B + (size_t)(gi * 8 + srow) * ldb + scol;
    da[q] = gi * 512;                             // shorts (8 rows x 64)
  }

  auto stage = [&](int bo, int k0) {
#pragma unroll
    for (int q = 0; q < 4; ++q) gload_lds16(sa[q] + k0, lds + bo + da[q]);
#pragma unroll
    for (int q = 0; q < 4; ++q) gload_lds16(sb[q] + k0, lds + bo + 16384 + da[q]);
  };

  auto compute = [&](int bo) {
    const short* sA = lds + bo;
    const short* sB = lds + bo + 16384;
#pragma unroll
    for (int kk = 0; kk < 2; ++kk) {
      short8 af[8], bb[4];
#pragma unroll
      for (int m = 0; m < 8; ++m)
        af[m] = *(const short8*)(sA + (wr * 128 + m * 16 + fr) * 64 + kk * 32 + fg * 8);
#pragma unroll
      for (int n = 0; n < 4; ++n)
        bb[n] = *(const short8*)(sB + (wc * 64 + n * 16 + fr) * 64 + kk * 32 + fg * 8);
#pragma unroll
      for (int m = 0; m < 8; ++m)
#pragma unroll
        for (int n = 0; n < 4; ++n)
          acc[m][n] = __builtin_amdgcn_mfma_f32_16x16x32_bf16(af[m], bb[n], acc[m][n], 0, 0, 0);
    }
  };

  stage(0, 0);
  __syncthreads();                 // drains vmcnt(0): tile 0 visible
  int bo = 0;
  const int nt = K >> 6;
  for (int t = 0; t < nt - 1; ++t) {
    stage(bo ^ 32768, (t + 1) << 6);  // prefetch next tile into other buffer
    compute(bo);
    __syncthreads();               // drains vmcnt(0): prefetch landed; reads done
    bo ^= 32768;
  }
  compute(bo);
}

#define ZERO_ACC8(acc)                       \
  {                                          \
    f32x4 _z = {0.f, 0.f, 0.f, 0.f};         \
    _Pragma("unroll")                        \
    for (int m = 0; m < 8; ++m)              \
      _Pragma("unroll")                      \
      for (int n = 0; n < 4; ++n) acc[m][n] = _z; \
  }

// ---------------------------------------------------------------------------
// legacy 128x128 core (kept for the small YbT GEMM; 256 blocks there)
// ---------------------------------------------------------------------------
__device__ __forceinline__ void gemm_core_nt(const short* __restrict__ A,
                                             const short* __restrict__ B,
                                             int K, int lda, int ldb,
                                             short* smem, f32x4 acc[4][4]) {
  const int tid  = threadIdx.x;
  const int wid  = tid >> 6;
  const int lane = tid & 63;
  const int wr = wid >> 1, wc = wid & 1;
  const int sr = lane >> 2;
  const int sc = (lane & 3) << 3;
  const int fr = lane & 15, fg = lane >> 4;
  short* sA = smem;
  short* sB = smem + 4096;
  short* dA0 = sA + wid * 512;
  short* dA1 = sA + 2048 + wid * 512;
  short* dB0 = sB + wid * 512;
  short* dB1 = sB + 2048 + wid * 512;
  const short* pa0 = A + (size_t)(wid * 16 + sr) * lda + sc;
  const short* pa1 = A + (size_t)(64 + wid * 16 + sr) * lda + sc;
  const short* pb0 = B + (size_t)(wid * 16 + sr) * ldb + sc;
  const short* pb1 = B + (size_t)(64 + wid * 16 + sr) * ldb + sc;

  for (int k0 = 0; k0 < K; k0 += 32) {
    gload_lds16(pa0 + k0, dA0);
    gload_lds16(pa1 + k0, dA1);
    gload_lds16(pb0 + k0, dB0);
    gload_lds16(pb1 + k0, dB1);
    __syncthreads();
    short8 af[4], bb[4];
#pragma unroll
    for (int m = 0; m < 4; ++m)
      af[m] = *(const short8*)(sA + (wr * 64 + m * 16 + fr) * 32 + fg * 8);
#pragma unroll
    for (int n = 0; n < 4; ++n)
      bb[n] = *(const short8*)(sB + (wc * 64 + n * 16 + fr) * 32 + fg * 8);
#pragma unroll
    for (int m = 0; m < 4; ++m)
#pragma unroll
      for (int n = 0; n < 4; ++n)
        acc[m][n] = __builtin_amdgcn_mfma_f32_16x16x32_bf16(af[m], bb[n], acc[m][n], 0, 0, 0);
    __syncthreads();
  }
}

#define ZERO_ACC4(acc)                       \
  {                                          \
    f32x4 _z = {0.f, 0.f, 0.f, 0.f};         \
    _Pragma("unroll")                        \
    for (int m = 0; m < 4; ++m)              \
      _Pragma("unroll")                      \
      for (int n = 0; n < 4; ++n) acc[m][n] = _z; \
  }

// K1: x (f32) -> xb (bf16), sq[i] = sum x[i]^2. One wave per row.
__global__ __launch_bounds__(256) void k_prep_x(const float* __restrict__ x,
                                                short* __restrict__ xb,
                                                float* __restrict__ sq) {
  const int row  = blockIdx.x * 4 + (threadIdx.x >> 6);
  const int lane = threadIdx.x & 63;
  const float* px = x + (size_t)row * DIM + lane * 8;
  const float4 v0 = *(const float4*)px;
  const float4 v1 = *(const float4*)(px + 4);
  float s = v0.x*v0.x + v0.y*v0.y + v0.z*v0.z + v0.w*v0.w +
            v1.x*v1.x + v1.y*v1.y + v1.z*v1.z + v1.w*v1.w;
  short8 o;
  o[0]=f2bf(v0.x); o[1]=f2bf(v0.y); o[2]=f2bf(v0.z); o[3]=f2bf(v0.w);
  o[4]=f2bf(v1.x); o[5]=f2bf(v1.y); o[6]=f2bf(v1.z); o[7]=f2bf(v1.w);
  *(short8*)(xb + (size_t)row * DIM + lane * 8) = o;
#pragma unroll
  for (int m = 32; m >= 1; m >>= 1) s += __shfl_xor(s, m);
  if (lane == 0) sq[row] = s;
}

// K1b: W (f32) -> Wb (bf16)
__global__ __launch_bounds__(256) void k_prep_w(const float* __restrict__ W,
                                                short* __restrict__ Wb) {
  const int idx = blockIdx.x * 256 + threadIdx.x;
  const float4 v0 = *(const float4*)(W + (size_t)idx * 8);
  const float4 v1 = *(const float4*)(W + (size_t)idx * 8 + 4);
  short8 o;
  o[0]=f2bf(v0.x); o[1]=f2bf(v0.y); o[2]=f2bf(v0.z); o[3]=f2bf(v0.w);
  o[4]=f2bf(v1.x); o[5]=f2bf(v1.y); o[6]=f2bf(v1.z); o[7]=f2bf(v1.w);
  *(short8*)(Wb + (size_t)idx * 8) = o;
}

// K2: YbT[o][i] = bf16( sum_d Wb[o][d] * xb[i][d] )  (Y = x@W.T, transposed)
__global__ __launch_bounds__(256) void k_ybt(const short* __restrict__ xb,
                                             const short* __restrict__ Wb,
                                             short* __restrict__ YbT) {
  __shared__ short smem[8192];
  f32x4 acc[4][4];
  ZERO_ACC4(acc);
  const int rowBase = blockIdx.y * 128;  // o
  const int colBase = blockIdx.x * 128;  // i
  gemm_core_nt(Wb + (size_t)rowBase * DIM, xb + (size_t)colBase * DIM,
               DIM, DIM, DIM, smem, acc);
  const int lane = threadIdx.x & 63, wid = threadIdx.x >> 6;
  const int wr = wid >> 1, wc = wid & 1, fr = lane & 15, fg = lane >> 4;
#pragma unroll
  for (int m = 0; m < 4; ++m)
#pragma unroll
    for (int n = 0; n < 4; ++n)
#pragma unroll
      for (int r = 0; r < 4; ++r) {
        const int ro = rowBase + wr * 64 + m * 16 + fg * 4 + r;
        const int ci = colBase + wc * 64 + n * 16 + fr;
        YbT[(size_t)ro * NPTS + ci] = f2bf(acc[m][n][r]);
      }
}

// K3 (256^2 2-phase): P[i][j] = bf16(exp(min(2*dot - si - sj,0)/2048)), rowsum +=
__global__ __launch_bounds__(512, 2) void k_pmat(const short* __restrict__ xb,
                                                 const float* __restrict__ sq,
                                                 short* __restrict__ P,
                                                 float* __restrict__ rowsum,
                                                 int jbase, int SW) {
  __shared__ short lds[65536];   // 128 KiB
  f32x4 acc[8][4];
  ZERO_ACC8(acc);
  const int rowBase = blockIdx.y * 256;      // i
  const int colTile = blockIdx.x * 256;      // j within strip
  const int jglob = jbase + colTile;
  gemm256_2ph(xb + (size_t)rowBase * DIM, xb + (size_t)jglob * DIM,
              DIM, DIM, DIM, lds, acc);
  const int lane = threadIdx.x & 63, wid = threadIdx.x >> 6;
  const int wr = wid >> 2, wc = wid & 3, fr = lane & 15, fg = lane >> 4;
  float sj[4];
#pragma unroll
  for (int n = 0; n < 4; ++n) sj[n] = sq[jglob + wc * 64 + n * 16 + fr];
#pragma unroll
  for (int m = 0; m < 8; ++m) {
#pragma unroll
    for (int r = 0; r < 4; ++r) {
      const int i = rowBase + wr * 128 + m * 16 + fg * 4 + r;
      const float si = sq[i];
      float rs = 0.f;
#pragma unroll
      for (int n = 0; n < 4; ++n) {
        const float t = fminf(2.f * acc[m][n][r] - si - sj[n], 0.f) * (1.0f / 2048.0f);
        const float w = __expf(t);
        rs += w;
        P[(size_t)i * SW + (colTile + wc * 64 + n * 16 + fr)] = f2bf(w);
      }
      rs += __shfl_xor(rs, 1);
      rs += __shfl_xor(rs, 2);
      rs += __shfl_xor(rs, 4);
      rs += __shfl_xor(rs, 8);
      if (fr == 0) atomicAdd(&rowsum[i], rs);
    }
  }
}

// K4 (256^2 2-phase): out_acc[i][o] += sum_j P[i][j] * YbT[o][j]  (z = K-split)
__global__ __launch_bounds__(512, 2) void k_pv(const short* __restrict__ P,
                                               const short* __restrict__ YbT,
                                               float* __restrict__ out_acc,
                                               int jbase, int SW, int klen) {
  __shared__ short lds[65536];   // 128 KiB
  f32x4 acc[8][4];
  ZERO_ACC8(acc);
  const int rowBase = blockIdx.y * 256;  // i
  const int colBase = blockIdx.x * 256;  // o
  const int kz = blockIdx.z * klen;
  gemm256_2ph(P + (size_t)rowBase * SW + kz,
              YbT + (size_t)colBase * NPTS + jbase + kz,
              klen, SW, NPTS, lds, acc);
  const int lane = threadIdx.x & 63, wid = threadIdx.x >> 6;
  const int wr = wid >> 2, wc = wid & 3, fr = lane & 15, fg = lane >> 4;
#pragma unroll
  for (int m = 0; m < 8; ++m)
#pragma unroll
    for (int n = 0; n < 4; ++n)
#pragma unroll
      for (int r = 0; r < 4; ++r) {
        const int i = rowBase + wr * 128 + m * 16 + fg * 4 + r;
        const int o = colBase + wc * 64 + n * 16 + fr;
        atomicAdd(&out_acc[(size_t)i * ODIM + o], acc[m][n][r]);
      }
}

// K5: out = out_acc / (rowsum + eps) + b
__global__ __launch_bounds__(256) void k_final(const float* __restrict__ out_acc,
                                               const float* __restrict__ rowsum,
                                               const float* __restrict__ bvec,
                                               float* __restrict__ out) {
  const int idx = blockIdx.x * 256 + threadIdx.x;
  const int i = idx >> 7;
  const int o = (idx & 127) << 2;
  const float inv = 1.f / (rowsum[i] + 1e-8f);
  const float4 a = *(const float4*)(out_acc + (size_t)i * ODIM + o);
  const float4 bb = *(const float4*)(bvec + o);
  float4 r;
  r.x = a.x * inv + bb.x;
  r.y = a.y * inv + bb.y;
  r.z = a.z * inv + bb.z;
  r.w = a.w * inv + bb.w;
  *(float4*)(out + (size_t)i * ODIM + o) = r;
}

extern "C" void kernel_launch(void* const* d_in, const int* in_sizes, int n_in,
                              void* d_out, int out_size, void* d_ws, size_t ws_size,
                              hipStream_t stream) {
  (void)in_sizes; (void)n_in; (void)out_size;
  const float* x = (const float*)d_in[0];
  const float* W = (const float*)d_in[1];
  const float* bvec = (const float*)d_in[2];
  float* out = (float*)d_out;
  char* ws = (char*)d_ws;

  // workspace carving (bytes)
  short* xb      = (short*)(ws + 0);                  //  8 MiB
  short* Wb      = (short*)(ws + 8388608);            //  0.5 MiB
  short* YbT     = (short*)(ws + 8912896);            //  8 MiB
  float* sq      = (float*)(ws + 17301504);           //  32 KiB
  float* rowsum  = (float*)(ws + 17334272);           //  32 KiB
  float* out_acc = (float*)(ws + 17367040);           //  16 MiB
  short* P       = (short*)(ws + 34144256);           //  up to 128 MiB

  // adaptive P-strip width so everything fits in ws (multiples of 256)
  size_t pav = ws_size > 34144256 ? ws_size - 34144256 : 0;
  int SW = 8192;
  while (SW > 256 && (size_t)NPTS * SW * 2 > pav) SW >>= 1;
  const int nstrips = NPTS / SW;
  int ksplit = SW / 2048;
  if (ksplit < 1) ksplit = 1;
  if (ksplit > 4) ksplit = 4;
  const int klen = SW / ksplit;

  hipMemsetAsync(rowsum, 0, NPTS * sizeof(float), stream);
  hipMemsetAsync(out_acc, 0, (size_t)NPTS * ODIM * sizeof(float), stream);

  k_prep_x<<<dim3(NPTS / 4), 256, 0, stream>>>(x, xb, sq);
  k_prep_w<<<dim3(ODIM * DIM / 8 / 256), 256, 0, stream>>>(W, Wb);
  k_ybt<<<dim3(NPTS / 128, ODIM / 128), 256, 0, stream>>>(xb, Wb, YbT);

  for (int s = 0; s < nstrips; ++s) {
    const int jbase = s * SW;
    k_pmat<<<dim3(SW / 256, NPTS / 256), 512, 0, stream>>>(xb, sq, P, rowsum, jbase, SW);
    k_pv<<<dim3(ODIM / 256, NPTS / 256, ksplit), 512, 0, stream>>>(P, YbT, out_acc, jbase, SW, klen);
  }

  k_final<<<dim3(NPTS * ODIM / 4 / 256), 256, 0, stream>>>(out_acc, rowsum, bvec, out);
}